// Round 9
// baseline (106.807 us; speedup 1.0000x reference)
//
#include <hip/hip_runtime.h>
#include <math.h>

#define D 128
#define P_MAX 64        // plane capacity (max in-degree before overflow path)
#define OCAP 65536      // overflow edge capacity
#define CHUNK 2048      // edges per chunk in k_rank
#define NSLICE 4        // k_rank dst slices

using bf16x8 = __attribute__((ext_vector_type(8))) short;
using f32x4  = __attribute__((ext_vector_type(4))) float;

__device__ __forceinline__ float int_or_float(const void* p) {
    int iv = *(const int*)p;
    if (iv > -1000000 && iv < 1000000) return (float)iv;
    return __int_as_float(iv);
}

__device__ __forceinline__ unsigned bf16_rne(float f) {
    unsigned u = __float_as_uint(f);
    return (u + 0x7fffu + ((u >> 16) & 1u)) >> 16;
}
__device__ __forceinline__ unsigned pack_bf2(float a, float b) {
    return bf16_rne(a) | (bf16_rne(b) << 16);
}

// ============================ TIER-1 kernels =============================

// k_rank: deg count + plane-format CSR in one pass, dst-sliced.
__global__ __launch_bounds__(256) void k_rank(const int* __restrict__ src,
                                              const int* __restrict__ dst,
                                              int* __restrict__ deg,
                                              int* __restrict__ planes,
                                              int* __restrict__ cnt,
                                              int2* __restrict__ opairs,
                                              int E, int n) {
    const int slice = blockIdx.x & (NSLICE - 1);
    const int chunk = blockIdx.x / NSLICE;
    int base = chunk * CHUNK;
    int end = base + CHUNK;
    if (end > E) end = E;
    for (int i = base + threadIdx.x; i < end; i += 256) {
        int t = dst[i];
        if (((t >> 4) & (NSLICE - 1)) == slice) {
            int s = src[i];
            int rk = atomicAdd(&deg[t], 1);
            if (rk < P_MAX) {
                planes[rk * n + t] = s;
            } else {
                int o = atomicAdd(cnt, 1);
                if (o < OCAP) opairs[o] = make_int2(s, t);
            }
        }
    }
}

// k_scale8: int8 quantization of x*dinv with per-row scale, split into two
// 64-col half tables (3.2 MB each -> per-pass gather working set fits L2).
// Biased ubytes q = rn(v*127/rowmax)+128; sxs[r] = rowmax/127. Row n = zeros.
__global__ __launch_bounds__(256) void k_scale8(const float4* __restrict__ x4,
                                                const int* __restrict__ deg,
                                                uint2* __restrict__ xlo,
                                                uint2* __restrict__ xhi,
                                                float* __restrict__ sxs, int n) {
    int gid = blockIdx.x * 256 + threadIdx.x;
    int r = gid >> 4;
    if (r > n) return;
    int q = gid & 15;
    uint2* half = (q < 8) ? xlo : xhi;
    int qq = q & 7;
    if (r == n) {
        half[(size_t)r * 8 + qq] = make_uint2(0u, 0u);
        if (q == 0) sxs[n] = 0.f;
        return;
    }
    int d = deg[r];
    if (d < 1) d = 1;
    float di = rsqrtf((float)d);
    float4 v0 = x4[(size_t)r * 32 + q * 2];
    float4 v1 = x4[(size_t)r * 32 + q * 2 + 1];
    float f[8] = {v0.x * di, v0.y * di, v0.z * di, v0.w * di,
                  v1.x * di, v1.y * di, v1.z * di, v1.w * di};
    float m = 0.f;
    #pragma unroll
    for (int i = 0; i < 8; ++i) m = fmaxf(m, fabsf(f[i]));
    #pragma unroll
    for (int off = 1; off < 16; off <<= 1)
        m = fmaxf(m, __shfl_xor(m, off, 16));
    float s = m * (1.f / 127.f);
    float rs = m > 0.f ? 127.f / m : 0.f;
    unsigned b[8];
    #pragma unroll
    for (int i = 0; i < 8; ++i)
        b[i] = (unsigned)(__float2int_rn(f[i] * rs) + 128);
    uint2 o;
    o.x = b[0] | (b[1] << 8) | (b[2] << 16) | (b[3] << 24);
    o.y = b[4] | (b[5] << 8) | (b[6] << 16) | (b[7] << 24);
    half[(size_t)r * 8 + qq] = o;
    if (q == 0) sxs[r] = s;
}

// dequant-accumulate 4 biased ubytes: a[i] += (float)byte_i * s
__device__ __forceinline__ void accq4(float* a, unsigned v, float s) {
    a[0] += (float)(v & 0xffu) * s;
    a[1] += (float)((v >> 8) & 0xffu) * s;
    a[2] += (float)((v >> 16) & 0xffu) * s;
    a[3] += (float)(v >> 24) * s;
}

// k_prepw2: Wm = theta*W + (1-theta)*I, bf16, in MFMA B-fragment order.
__global__ __launch_bounds__(256) void k_prepw2(const float* __restrict__ W,
                                                uint4* __restrict__ wmt,
                                                const float* __restrict__ lamda_p,
                                                const void* __restrict__ l_p) {
    int tid = blockIdx.x * 256 + threadIdx.x;
    if (tid >= 2048) return;
    float lamda = *lamda_p;
    float lf = int_or_float(l_p);
    float theta = logf(lamda / lf + 1.0f);
    float omt = 1.0f - theta;
    int ct = tid >> 8, kb = (tid >> 6) & 3, kg = (tid >> 4) & 3, lc = tid & 15;
    int c = ct * 16 + lc;
    int k0 = kb * 32 + kg * 8;
    float v[8];
    #pragma unroll
    for (int j = 0; j < 8; ++j) {
        float wv = theta * W[(size_t)(k0 + j) * D + c];
        if (k0 + j == c) wv += omt;
        v[j] = wv;
    }
    uint4 o;
    o.x = pack_bf2(v[0], v[1]);
    o.y = pack_bf2(v[2], v[3]);
    o.z = pack_bf2(v[4], v[5]);
    o.w = pack_bf2(v[6], v[7]);
    wmt[tid] = o;
}

// one gather pass over a 64-col half table; writes 4 bf16 support elems to
// the swizzled LDS tile.
__device__ __forceinline__ void gather_half(
        const unsigned* __restrict__ xs, const float* __restrict__ sxs,
        const int* __restrict__ planes, const int* __restrict__ cnt,
        const int2* __restrict__ opairs, const float4* __restrict__ h04,
        uint4* sS, int r, int rc, int d, int dc, int n, int g, int q,
        float alpha, int colhalf) {
    float a0[4] = {}, a1[4] = {}, a2[4] = {}, a3[4] = {};
    float ssum = 0.f;
    for (int p = 0; p < dc; p += 8) {
        int pi0 = (p + 0 < dc) ? (p + 0) : 0;
        int pi1 = (p + 1 < dc) ? (p + 1) : 0;
        int pi2 = (p + 2 < dc) ? (p + 2) : 0;
        int pi3 = (p + 3 < dc) ? (p + 3) : 0;
        int pi4 = (p + 4 < dc) ? (p + 4) : 0;
        int pi5 = (p + 5 < dc) ? (p + 5) : 0;
        int pi6 = (p + 6 < dc) ? (p + 6) : 0;
        int pi7 = (p + 7 < dc) ? (p + 7) : 0;
        int t0 = planes[(size_t)pi0 * n + rc];
        int t1 = planes[(size_t)pi1 * n + rc];
        int t2 = planes[(size_t)pi2 * n + rc];
        int t3 = planes[(size_t)pi3 * n + rc];
        int t4 = planes[(size_t)pi4 * n + rc];
        int t5 = planes[(size_t)pi5 * n + rc];
        int t6 = planes[(size_t)pi6 * n + rc];
        int t7 = planes[(size_t)pi7 * n + rc];
        int s0 = (p + 0 < dc) ? t0 : n;   // n = zero dummy row (scale 0)
        int s1 = (p + 1 < dc) ? t1 : n;
        int s2 = (p + 2 < dc) ? t2 : n;
        int s3 = (p + 3 < dc) ? t3 : n;
        int s4 = (p + 4 < dc) ? t4 : n;
        int s5 = (p + 5 < dc) ? t5 : n;
        int s6 = (p + 6 < dc) ? t6 : n;
        int s7 = (p + 7 < dc) ? t7 : n;
        float c0 = sxs[s0], c1 = sxs[s1], c2 = sxs[s2], c3 = sxs[s3];
        float c4 = sxs[s4], c5 = sxs[s5], c6 = sxs[s6], c7 = sxs[s7];
        unsigned v0 = xs[(size_t)s0 * 16 + q];
        unsigned v1 = xs[(size_t)s1 * 16 + q];
        unsigned v2 = xs[(size_t)s2 * 16 + q];
        unsigned v3 = xs[(size_t)s3 * 16 + q];
        unsigned v4 = xs[(size_t)s4 * 16 + q];
        unsigned v5 = xs[(size_t)s5 * 16 + q];
        unsigned v6 = xs[(size_t)s6 * 16 + q];
        unsigned v7 = xs[(size_t)s7 * 16 + q];
        accq4(a0, v0, c0);
        accq4(a1, v1, c1);
        accq4(a2, v2, c2);
        accq4(a3, v3, c3);
        accq4(a0, v4, c4);
        accq4(a1, v5, c5);
        accq4(a2, v6, c6);
        accq4(a3, v7, c7);
        ssum += ((c0 + c1) + (c2 + c3)) + ((c4 + c5) + (c6 + c7));
    }
    if (d > P_MAX) {                // never taken in practice (cnt == 0)
        int c = *cnt;
        if (c > OCAP) c = OCAP;
        for (int i = 0; i < c; ++i) {
            int2 pr = opairs[i];
            if (pr.y == r) {
                float cs = sxs[pr.x];
                unsigned v = xs[(size_t)pr.x * 16 + q];
                accq4(a0, v, cs);
                ssum += cs;
            }
        }
    }
    float di = rsqrtf((float)(d < 1 ? 1 : d));
    float ca = (1.0f - alpha) * di;
    float corr = 128.f * ssum;
    float4 hb = h04[(size_t)rc * 32 + colhalf * 16 + q];
    float s0 = ca * (((a0[0] + a1[0]) + (a2[0] + a3[0])) - corr) + alpha * hb.x;
    float s1 = ca * (((a0[1] + a1[1]) + (a2[1] + a3[1])) - corr) + alpha * hb.y;
    float s2 = ca * (((a0[2] + a1[2]) + (a2[2] + a3[2])) - corr) + alpha * hb.z;
    float s3 = ca * (((a0[3] + a1[3]) + (a2[3] + a3[3])) - corr) + alpha * hb.w;
    uint2 o;
    o.x = pack_bf2(s0, s1);
    o.y = pack_bf2(s2, s3);
    int gran = (colhalf * 8 + (q >> 1)) ^ (g & 7);
    *(uint2*)((char*)sS + g * 256 + gran * 16 + (q & 1) * 8) = o;
}

// k_fused: two-pass int8 gather (lo/hi half tables) + support + MFMA GEMM +
// residual. Block = 256 threads = 4 waves, 16 output rows.
__global__ __launch_bounds__(256) void k_fused(
        const unsigned* __restrict__ xlo, const unsigned* __restrict__ xhi,
        const float* __restrict__ sxs, const int* __restrict__ planes,
        const int* __restrict__ deg, const int* __restrict__ cnt,
        const int2* __restrict__ opairs, const float* __restrict__ h0,
        const float* __restrict__ alpha_p, const uint4* __restrict__ wmt,
        float* __restrict__ out, const float* __restrict__ x, int n) {
    __shared__ uint4 sS[256];           // 16 rows x 256 B, swizzled (4 KB)
    const int t = threadIdx.x;
    const int base = blockIdx.x * 16;

    {
        const int g = t >> 4;           // row group 0..15
        const int q = t & 15;
        int r = base + g;
        int rc = r < n ? r : 0;
        int d = r < n ? deg[rc] : 0;
        int dc = d < P_MAX ? d : P_MAX;
        float alpha = *alpha_p;
        const float4* h04 = (const float4*)h0;
        gather_half(xlo, sxs, planes, cnt, opairs, h04, sS,
                    r, rc, d, dc, n, g, q, alpha, 0);
        gather_half(xhi, sxs, planes, cnt, opairs, h04, sS,
                    r, rc, d, dc, n, g, q, alpha, 1);
    }
    __syncthreads();

    const int lane = t & 63;
    const int wv = t >> 6;              // wave 0..3
    const int lr = lane & 15;
    const int kg = lane >> 4;

    bf16x8 a[4];
    #pragma unroll
    for (int kb = 0; kb < 4; ++kb)
        a[kb] = ((const bf16x8*)sS)[lr * 16 + ((kb * 4 + kg) ^ (lr & 7))];

    const bf16x8* wfr = (const bf16x8*)wmt;
    #pragma unroll
    for (int j = 0; j < 2; ++j) {
        int ct = wv * 2 + j;
        f32x4 acc = (f32x4){0.f, 0.f, 0.f, 0.f};
        #pragma unroll
        for (int kb = 0; kb < 4; ++kb) {
            bf16x8 b = wfr[ct * 256 + kb * 64 + lane];
            acc = __builtin_amdgcn_mfma_f32_16x16x32_bf16(a[kb], b, acc, 0, 0, 0);
        }
        int c = ct * 16 + lr;
        #pragma unroll
        for (int reg = 0; reg < 4; ++reg) {
            int rr = base + kg * 4 + reg;
            if (rr < n) {
                size_t off = (size_t)rr * D + c;
                out[off] = acc[reg] + x[off];
            }
        }
    }
}

// ==================== TIER-2 (old CSR path) kernels ======================

__global__ __launch_bounds__(256) void k_deg(const int* __restrict__ dst,
                                             int* __restrict__ deg, int E) {
    int i = blockIdx.x * 256 + threadIdx.x;
    if (i < E) atomicAdd(&deg[dst[i]], 1);
}

__global__ __launch_bounds__(256) void k_dinv(int* dd, int n) {
    int i = blockIdx.x * 256 + threadIdx.x;
    if (i < n) {
        int d = dd[i];
        if (d < 1) d = 1;
        ((float*)dd)[i] = rsqrtf((float)d);
    }
}

__global__ __launch_bounds__(256) void k_scan1(const int* __restrict__ deg,
                                               int* __restrict__ bsum, int n) {
    __shared__ int red[256];
    int b = blockIdx.x, t = threadIdx.x;
    int base = b * 1024;
    int s = 0;
    #pragma unroll
    for (int i = 0; i < 4; ++i) {
        int idx = base + i * 256 + t;
        if (idx < n) s += deg[idx];
    }
    red[t] = s;
    __syncthreads();
    for (int k = 128; k > 0; k >>= 1) {
        if (t < k) red[t] += red[t + k];
        __syncthreads();
    }
    if (t == 0) bsum[b] = red[0];
}

__global__ void k_scan2(const int* __restrict__ bsum, int* __restrict__ boff,
                        int* __restrict__ offsets, int nb, int n) {
    if (threadIdx.x == 0) {
        int acc = 0;
        for (int i = 0; i < nb; ++i) { boff[i] = acc; acc += bsum[i]; }
        offsets[n] = acc;
    }
}

__global__ __launch_bounds__(256) void k_scan3(int* __restrict__ deg,
                                               const int* __restrict__ boff,
                                               int* __restrict__ offsets,
                                               int* __restrict__ cursor, int n) {
    __shared__ int ls[256];
    int b = blockIdx.x, t = threadIdx.x;
    int base = b * 1024 + t * 4;
    int v[4];
    #pragma unroll
    for (int i = 0; i < 4; ++i) v[i] = (base + i < n) ? deg[base + i] : 0;
    int mysum = v[0] + v[1] + v[2] + v[3];
    ls[t] = mysum;
    __syncthreads();
    for (int k = 1; k < 256; k <<= 1) {
        int add = (t >= k) ? ls[t - k] : 0;
        __syncthreads();
        ls[t] += add;
        __syncthreads();
    }
    int p = boff[b] + ls[t] - mysum;
    #pragma unroll
    for (int i = 0; i < 4; ++i) {
        if (base + i < n) {
            offsets[base + i] = p;
            cursor[base + i] = p;
            int d = v[i] < 1 ? 1 : v[i];
            ((float*)deg)[base + i] = rsqrtf((float)d);
        }
        p += v[i];
    }
}

__global__ __launch_bounds__(256) void k_csr(const int* __restrict__ src,
                                             const int* __restrict__ dst,
                                             int* __restrict__ cursor,
                                             int* __restrict__ csr_src, int E) {
    int i = blockIdx.x * 256 + threadIdx.x;
    if (i < E) {
        int pos = atomicAdd(&cursor[dst[i]], 1);
        csr_src[pos] = src[i];
    }
}

__global__ __launch_bounds__(256) void k_gather(const float4* __restrict__ x4,
                                                const int* __restrict__ csr_src,
                                                const int* __restrict__ offsets,
                                                const float* __restrict__ dinv,
                                                float4* __restrict__ hacc, int n) {
    int idx = blockIdx.x * 256 + threadIdx.x;
    int r = idx >> 5;
    if (r >= n) return;
    int q = idx & 31;
    int e0 = offsets[r], e1 = offsets[r + 1];
    float4 a0 = make_float4(0.f, 0.f, 0.f, 0.f);
    float4 a1 = make_float4(0.f, 0.f, 0.f, 0.f);
    float4 a2 = make_float4(0.f, 0.f, 0.f, 0.f);
    float4 a3 = make_float4(0.f, 0.f, 0.f, 0.f);
    int e = e0;
    for (; e + 4 <= e1; e += 4) {
        int s0 = csr_src[e + 0];
        int s1 = csr_src[e + 1];
        int s2 = csr_src[e + 2];
        int s3 = csr_src[e + 3];
        float c0 = dinv[s0], c1 = dinv[s1], c2 = dinv[s2], c3 = dinv[s3];
        float4 v0 = x4[(size_t)s0 * (D / 4) + q];
        float4 v1 = x4[(size_t)s1 * (D / 4) + q];
        float4 v2 = x4[(size_t)s2 * (D / 4) + q];
        float4 v3 = x4[(size_t)s3 * (D / 4) + q];
        a0.x += v0.x * c0; a0.y += v0.y * c0; a0.z += v0.z * c0; a0.w += v0.w * c0;
        a1.x += v1.x * c1; a1.y += v1.y * c1; a1.z += v1.z * c1; a1.w += v1.w * c1;
        a2.x += v2.x * c2; a2.y += v2.y * c2; a2.z += v2.z * c2; a2.w += v2.w * c2;
        a3.x += v3.x * c3; a3.y += v3.y * c3; a3.z += v3.z * c3; a3.w += v3.w * c3;
    }
    for (; e < e1; ++e) {
        int s = csr_src[e];
        float c = dinv[s];
        float4 v = x4[(size_t)s * (D / 4) + q];
        a0.x += v.x * c; a0.y += v.y * c; a0.z += v.z * c; a0.w += v.w * c;
    }
    float4 acc;
    acc.x = (a0.x + a1.x) + (a2.x + a3.x);
    acc.y = (a0.y + a1.y) + (a2.y + a3.y);
    acc.z = (a0.z + a1.z) + (a2.z + a3.z);
    acc.w = (a0.w + a1.w) + (a2.w + a3.w);
    hacc[(size_t)r * (D / 4) + q] = acc;
}

__global__ __launch_bounds__(256) void k_scatter(const float4* __restrict__ x4,
                                                 const int* __restrict__ src,
                                                 const int* __restrict__ dst,
                                                 const float* __restrict__ dinv,
                                                 float* hacc, int E) {
    int idx = blockIdx.x * 256 + threadIdx.x;
    int e = idx >> 5;
    if (e >= E) return;
    int q = idx & 31;
    int s = src[e];
    int t = dst[e];
    float sc = dinv[s];
    float4 v = x4[(size_t)s * (D / 4) + q];
    float* h = hacc + (size_t)t * D + q * 4;
    unsafeAtomicAdd(h + 0, v.x * sc);
    unsafeAtomicAdd(h + 1, v.y * sc);
    unsafeAtomicAdd(h + 2, v.z * sc);
    unsafeAtomicAdd(h + 3, v.w * sc);
}

// old VALU epilogue (fallback paths)
__global__ __launch_bounds__(256) void k_final(float* io,
                                               const float* __restrict__ dinv,
                                               const float* __restrict__ h0,
                                               const float* __restrict__ x,
                                               const float* __restrict__ W,
                                               const float* __restrict__ lamda_p,
                                               const float* __restrict__ alpha_p,
                                               const void* __restrict__ l_p,
                                               int n) {
    __shared__ float sW[D * D];
    __shared__ float sSup[32][D];
    const int t = threadIdx.x;

    {
        const float4* W4 = (const float4*)W;
        float4* sW4 = (float4*)sW;
        #pragma unroll
        for (int i = 0; i < (D * D / 4) / 256; ++i)
            sW4[i * 256 + t] = W4[i * 256 + t];
    }

    const float alpha = *alpha_p;
    const float lamda = *lamda_p;
    const float lf = int_or_float(l_p);
    const float theta = logf(lamda / lf + 1.0f);
    const float omt = 1.0f - theta;
    const float oma = 1.0f - alpha;

    const int base = blockIdx.x * 32;

    {
        const float4* hacc4 = (const float4*)io;
        const float4* h04 = (const float4*)h0;
        #pragma unroll
        for (int i = 0; i < 4; ++i) {
            int v = i * 256 + t;
            int tr = v >> 5;
            int q = v & 31;
            int r = base + tr;
            float4 sup = make_float4(0.f, 0.f, 0.f, 0.f);
            if (r < n) {
                float ca = oma * dinv[r];
                float4 a = hacc4[(size_t)r * (D / 4) + q];
                float4 b = h04[(size_t)r * (D / 4) + q];
                sup.x = ca * a.x + alpha * b.x;
                sup.y = ca * a.y + alpha * b.y;
                sup.z = ca * a.z + alpha * b.z;
                sup.w = ca * a.w + alpha * b.w;
            }
            *(float4*)&sSup[tr][q * 4] = sup;
        }
    }
    __syncthreads();

    const int cg = t & 31;
    const int rb = t >> 5;
    float acc[4][4] = {};
    const float4* sW4 = (const float4*)sW;
    #pragma unroll 4
    for (int k = 0; k < D; ++k) {
        float4 w = sW4[k * 32 + cg];
        #pragma unroll
        for (int j = 0; j < 4; ++j) {
            float s = sSup[rb * 4 + j][k];
            acc[j][0] += s * w.x;
            acc[j][1] += s * w.y;
            acc[j][2] += s * w.z;
            acc[j][3] += s * w.w;
        }
    }

    #pragma unroll
    for (int j = 0; j < 4; ++j) {
        int tr = rb * 4 + j;
        int r = base + tr;
        if (r < n) {
            float4 xi = ((const float4*)x)[(size_t)r * (D / 4) + cg];
            float4 sp = *(const float4*)&sSup[tr][cg * 4];
            float4 o;
            o.x = theta * acc[j][0] + omt * sp.x + xi.x;
            o.y = theta * acc[j][1] + omt * sp.y + xi.y;
            o.z = theta * acc[j][2] + omt * sp.z + xi.z;
            o.w = theta * acc[j][3] + omt * sp.w + xi.w;
            ((float4*)io)[(size_t)r * (D / 4) + cg] = o;
        }
    }
}

// ================================ host ===================================

extern "C" void kernel_launch(void* const* d_in, const int* in_sizes, int n_in,
                              void* d_out, int out_size, void* d_ws, size_t ws_size,
                              hipStream_t stream) {
    const float* x = (const float*)d_in[0];
    const int* esrc = (const int*)d_in[1];
    const int* edst = (const int*)d_in[2];
    const float* h0 = (const float*)d_in[3];
    const float* W = (const float*)d_in[4];
    const float* lamda_p = (const float*)d_in[5];
    const float* alpha_p = (const float*)d_in[6];
    const void* l_p = d_in[7];

    const int E = in_sizes[1];
    const int n = in_sizes[0] / D;

    char* w = (char*)d_ws;

    // ---- tier-1 layout ----
    size_t o_deg = 0;                                            // n ints
    size_t o_cnt = ((size_t)n * 4 + 15) & ~15ull;                // 1 int (+pad)
    size_t o_op  = o_cnt + 16;                                   // OCAP int2
    size_t o_xlo = (o_op + (size_t)OCAP * 8 + 15) & ~15ull;      // (n+1)*64 u8
    size_t o_xhi = (o_xlo + (size_t)(n + 1) * 64 + 15) & ~15ull; // (n+1)*64 u8
    size_t o_sx  = (o_xhi + (size_t)(n + 1) * 64 + 15) & ~15ull; // (n+1) floats
    size_t o_wmt = (o_sx + (size_t)(n + 1) * 4 + 15) & ~15ull;   // 32 KB
    size_t o_pl  = (o_wmt + 32768 + 15) & ~15ull;                // P_MAX*n ints
    size_t need1 = o_pl + (size_t)P_MAX * n * 4;

    if (ws_size >= need1) {
        int* deg = (int*)(w + o_deg);
        int* cnt = (int*)(w + o_cnt);
        int2* opairs = (int2*)(w + o_op);
        uint2* xlo = (uint2*)(w + o_xlo);
        uint2* xhi = (uint2*)(w + o_xhi);
        float* sxs = (float*)(w + o_sx);
        uint4* wmt = (uint4*)(w + o_wmt);
        int* planes = (int*)(w + o_pl);

        hipMemsetAsync(w, 0, o_cnt + 16, stream);   // deg + cnt

        int chunks = (E + CHUNK - 1) / CHUNK;
        k_prepw2<<<8, 256, 0, stream>>>(W, wmt, lamda_p, l_p);
        k_rank<<<chunks * NSLICE, 256, 0, stream>>>(esrc, edst, deg, planes,
                                                    cnt, opairs, E, n);
        k_scale8<<<((n + 1) * 16 + 255) / 256, 256, 0, stream>>>(
            (const float4*)x, deg, xlo, xhi, sxs, n);
        k_fused<<<(n + 15) / 16, 256, 0, stream>>>(
            (const unsigned*)xlo, (const unsigned*)xhi, sxs, planes, deg, cnt,
            opairs, h0, alpha_p, wmt, (float*)d_out, x, n);
        return;
    }

    // ---- tier-2: old CSR path ----
    const int nb = (n + 1023) / 1024;
    size_t t_deg = 0;
    size_t t_off = (t_deg + (size_t)n * 4 + 15) & ~15ull;
    size_t t_cur = (t_off + (size_t)(n + 1) * 4 + 15) & ~15ull;
    size_t t_bs  = (t_cur + (size_t)n * 4 + 15) & ~15ull;
    size_t t_bo  = (t_bs + (size_t)nb * 4 + 15) & ~15ull;
    size_t t_csr = (t_bo + (size_t)nb * 4 + 15) & ~15ull;
    size_t need2 = t_csr + (size_t)E * 4;

    int* deg = (int*)(w + t_deg);
    float* dinv = (float*)(w + t_deg);

    hipMemsetAsync(deg, 0, (size_t)n * sizeof(int), stream);
    k_deg<<<(E + 255) / 256, 256, 0, stream>>>(edst, deg, E);

    if (ws_size >= need2 && nb <= 1024) {
        int* offsets = (int*)(w + t_off);
        int* cursor  = (int*)(w + t_cur);
        int* bsum    = (int*)(w + t_bs);
        int* boff    = (int*)(w + t_bo);
        int* csr_src = (int*)(w + t_csr);

        k_scan1<<<nb, 256, 0, stream>>>(deg, bsum, n);
        k_scan2<<<1, 64, 0, stream>>>(bsum, boff, offsets, nb, n);
        k_scan3<<<nb, 256, 0, stream>>>(deg, boff, offsets, cursor, n);
        k_csr<<<(E + 255) / 256, 256, 0, stream>>>(esrc, edst, cursor, csr_src, E);
        k_gather<<<((size_t)n * 32 + 255) / 256, 256, 0, stream>>>(
            (const float4*)x, csr_src, offsets, dinv, (float4*)d_out, n);
    } else {
        k_dinv<<<(n + 255) / 256, 256, 0, stream>>>(deg, n);
        hipMemsetAsync(d_out, 0, (size_t)n * D * sizeof(float), stream);
        k_scatter<<<((size_t)E * 32 + 255) / 256, 256, 0, stream>>>(
            (const float4*)x, esrc, edst, dinv, (float*)d_out, E);
    }

    k_final<<<(n + 31) / 32, 256, 0, stream>>>(
        (float*)d_out, dinv, h0, x, W, lamda_p, alpha_p, l_p, n);
}

// Round 10
// 96.680 us; speedup vs baseline: 1.1047x; 1.1047x over previous
//
#include <hip/hip_runtime.h>
#include <math.h>

#define D 128
#define P_MAX 64        // plane capacity (max in-degree before overflow path)
#define OCAP 65536      // overflow edge capacity
#define CHUNK 2048      // edges per chunk in k_rank
#define NSLICE 4        // k_rank dst slices

using bf16x8 = __attribute__((ext_vector_type(8))) short;
using f32x4  = __attribute__((ext_vector_type(4))) float;

__device__ __forceinline__ float int_or_float(const void* p) {
    int iv = *(const int*)p;
    if (iv > -1000000 && iv < 1000000) return (float)iv;
    return __int_as_float(iv);
}

__device__ __forceinline__ unsigned bf16_rne(float f) {
    unsigned u = __float_as_uint(f);
    return (u + 0x7fffu + ((u >> 16) & 1u)) >> 16;
}
__device__ __forceinline__ unsigned pack_bf2(float a, float b) {
    return bf16_rne(a) | (bf16_rne(b) << 16);
}

// ============================ TIER-1 kernels =============================

// k_rank: deg count + plane-format CSR in one pass, dst-sliced.
__global__ __launch_bounds__(256) void k_rank(const int* __restrict__ src,
                                              const int* __restrict__ dst,
                                              int* __restrict__ deg,
                                              int* __restrict__ planes,
                                              int* __restrict__ cnt,
                                              int2* __restrict__ opairs,
                                              int E, int n) {
    const int slice = blockIdx.x & (NSLICE - 1);
    const int chunk = blockIdx.x / NSLICE;
    int base = chunk * CHUNK;
    int end = base + CHUNK;
    if (end > E) end = E;
    for (int i = base + threadIdx.x; i < end; i += 256) {
        int t = dst[i];
        if (((t >> 4) & (NSLICE - 1)) == slice) {
            int s = src[i];
            int rk = atomicAdd(&deg[t], 1);
            if (rk < P_MAX) {
                planes[rk * n + t] = s;
            } else {
                int o = atomicAdd(cnt, 1);
                if (o < OCAP) opairs[o] = make_int2(s, t);
            }
        }
    }
}

// k_scale8: int8 quantization of x*dinv with per-row scale, PLUS:
//  - blocks 0..7 also build Wm = theta*W + (1-theta)*I in MFMA B-frag order
//  - block 0 zeroes the xs8[-1]/sxs[-1] guards
//  - pads planes rows [dc, ceil8(dc)) with -1 so the gather loop is maskless
__global__ __launch_bounds__(256) void k_scale8(const float4* __restrict__ x4,
                                                const int* __restrict__ deg,
                                                uint2* __restrict__ xs8,
                                                float* __restrict__ sxs,
                                                int* __restrict__ planes,
                                                const float* __restrict__ W,
                                                uint4* __restrict__ wmt,
                                                const float* __restrict__ lamda_p,
                                                const void* __restrict__ l_p,
                                                int n) {
    const int t = threadIdx.x;
    if (blockIdx.x < 8) {               // merged prepw2 (tid 0..2047)
        int tid = blockIdx.x * 256 + t;
        float lamda = *lamda_p;
        float lf = int_or_float(l_p);
        float theta = logf(lamda / lf + 1.0f);
        float omt = 1.0f - theta;
        int ct = tid >> 8, kb = (tid >> 6) & 3, kg = (tid >> 4) & 3, lc = tid & 15;
        int c = ct * 16 + lc;
        int k0 = kb * 32 + kg * 8;
        float v[8];
        #pragma unroll
        for (int j = 0; j < 8; ++j) {
            float wv = theta * W[(size_t)(k0 + j) * D + c];
            if (k0 + j == c) wv += omt;
            v[j] = wv;
        }
        uint4 o;
        o.x = pack_bf2(v[0], v[1]);
        o.y = pack_bf2(v[2], v[3]);
        o.z = pack_bf2(v[4], v[5]);
        o.w = pack_bf2(v[6], v[7]);
        wmt[tid] = o;
    }
    if (blockIdx.x == 0) {              // zero guards (row index -1)
        if (t < 32) ((unsigned*)xs8)[(int)t - 32] = 0u;
        if (t == 32) sxs[-1] = 0.f;
    }
    int gid = blockIdx.x * 256 + t;
    int r = gid >> 4;
    if (r >= n) return;
    int q = gid & 15;
    int d = deg[r];
    int dcl = d < P_MAX ? d : P_MAX;
    if (q < 8) {                        // pad planes for maskless gather
        int c8 = (dcl + 7) & ~7;
        if (dcl + q < c8) planes[(size_t)(dcl + q) * n + r] = -1;
    }
    int dd = d < 1 ? 1 : d;
    float di = rsqrtf((float)dd);
    float4 v0 = x4[(size_t)r * 32 + q * 2];
    float4 v1 = x4[(size_t)r * 32 + q * 2 + 1];
    float f[8] = {v0.x * di, v0.y * di, v0.z * di, v0.w * di,
                  v1.x * di, v1.y * di, v1.z * di, v1.w * di};
    float m = 0.f;
    #pragma unroll
    for (int i = 0; i < 8; ++i) m = fmaxf(m, fabsf(f[i]));
    #pragma unroll
    for (int off = 1; off < 16; off <<= 1)
        m = fmaxf(m, __shfl_xor(m, off, 16));
    float s = m * (1.f / 127.f);
    float rs = m > 0.f ? 127.f / m : 0.f;
    unsigned b[8];
    #pragma unroll
    for (int i = 0; i < 8; ++i)
        b[i] = (unsigned)(__float2int_rn(f[i] * rs) + 128);
    uint2 o;
    o.x = b[0] | (b[1] << 8) | (b[2] << 16) | (b[3] << 24);
    o.y = b[4] | (b[5] << 8) | (b[6] << 16) | (b[7] << 24);
    xs8[(size_t)r * 16 + q] = o;
    if (q == 0) sxs[r] = s;
}

// dequant-accumulate 8 biased ubytes: a[i] += (float)byte_i * s
__device__ __forceinline__ void accq(float* a, uint2 v, float s) {
    a[0] += (float)(v.x & 0xffu) * s;
    a[1] += (float)((v.x >> 8) & 0xffu) * s;
    a[2] += (float)((v.x >> 16) & 0xffu) * s;
    a[3] += (float)(v.x >> 24) * s;
    a[4] += (float)(v.y & 0xffu) * s;
    a[5] += (float)((v.y >> 8) & 0xffu) * s;
    a[6] += (float)((v.y >> 16) & 0xffu) * s;
    a[7] += (float)(v.y >> 24) * s;
}

// k_fused: int8 gather (maskless, padded planes + guard row -1) + support +
// MFMA GEMM + residual. Block = 256 threads = 4 waves, 16 output rows.
__global__ __launch_bounds__(256) void k_fused(
        const uint2* __restrict__ xs8, const float* __restrict__ sxs,
        const int* __restrict__ planes, const int* __restrict__ deg,
        const int* __restrict__ cnt, const int2* __restrict__ opairs,
        const float* __restrict__ h0, const float* __restrict__ alpha_p,
        const uint4* __restrict__ wmt, float* __restrict__ out,
        const float* __restrict__ x, int n) {
    __shared__ uint4 sS[256];           // 16 rows x 256 B, swizzled (4 KB)
    const int t = threadIdx.x;
    const int base = blockIdx.x * 16;

    {
        const int g = t >> 4;           // row group 0..15
        const int q = t & 15;
        int r = base + g;
        int rc = r < n ? r : 0;
        int d = r < n ? deg[rc] : 0;
        int dc = d < P_MAX ? d : P_MAX;
        float a0[8] = {}, a1[8] = {}, a2[8] = {}, a3[8] = {};
        float ssum = 0.f;
        const char* xsb = (const char*)xs8;
        for (int p = 0; p < dc; p += 8) {
            int s0 = planes[(p + 0) * n + rc];   // padded entries are -1
            int s1 = planes[(p + 1) * n + rc];
            int s2 = planes[(p + 2) * n + rc];
            int s3 = planes[(p + 3) * n + rc];
            int s4 = planes[(p + 4) * n + rc];
            int s5 = planes[(p + 5) * n + rc];
            int s6 = planes[(p + 6) * n + rc];
            int s7 = planes[(p + 7) * n + rc];
            float c0 = sxs[s0], c1 = sxs[s1], c2 = sxs[s2], c3 = sxs[s3];
            float c4 = sxs[s4], c5 = sxs[s5], c6 = sxs[s6], c7 = sxs[s7];
            uint2 v0 = *(const uint2*)(xsb + (long)s0 * 128 + q * 8);
            uint2 v1 = *(const uint2*)(xsb + (long)s1 * 128 + q * 8);
            uint2 v2 = *(const uint2*)(xsb + (long)s2 * 128 + q * 8);
            uint2 v3 = *(const uint2*)(xsb + (long)s3 * 128 + q * 8);
            uint2 v4 = *(const uint2*)(xsb + (long)s4 * 128 + q * 8);
            uint2 v5 = *(const uint2*)(xsb + (long)s5 * 128 + q * 8);
            uint2 v6 = *(const uint2*)(xsb + (long)s6 * 128 + q * 8);
            uint2 v7 = *(const uint2*)(xsb + (long)s7 * 128 + q * 8);
            accq(a0, v0, c0);
            accq(a1, v1, c1);
            accq(a2, v2, c2);
            accq(a3, v3, c3);
            accq(a0, v4, c4);
            accq(a1, v5, c5);
            accq(a2, v6, c6);
            accq(a3, v7, c7);
            ssum += ((c0 + c1) + (c2 + c3)) + ((c4 + c5) + (c6 + c7));
        }
        if (d > P_MAX) {                // never taken in practice (cnt == 0)
            int c = *cnt;
            if (c > OCAP) c = OCAP;
            for (int i = 0; i < c; ++i) {
                int2 pr = opairs[i];
                if (pr.y == r) {
                    float cs = sxs[pr.x];
                    uint2 v = *(const uint2*)(xsb + (long)pr.x * 128 + q * 8);
                    accq(a0, v, cs);
                    ssum += cs;
                }
            }
        }
        float di = rsqrtf((float)(d < 1 ? 1 : d));
        float alpha = *alpha_p;
        float ca = (1.0f - alpha) * di;
        float corr = 128.f * ssum;
        const float4* h04 = (const float4*)h0;
        float4 hb0 = h04[(size_t)rc * 32 + q * 2];
        float4 hb1 = h04[(size_t)rc * 32 + q * 2 + 1];
        float s0 = ca * (((a0[0] + a1[0]) + (a2[0] + a3[0])) - corr) + alpha * hb0.x;
        float s1 = ca * (((a0[1] + a1[1]) + (a2[1] + a3[1])) - corr) + alpha * hb0.y;
        float s2 = ca * (((a0[2] + a1[2]) + (a2[2] + a3[2])) - corr) + alpha * hb0.z;
        float s3 = ca * (((a0[3] + a1[3]) + (a2[3] + a3[3])) - corr) + alpha * hb0.w;
        float s4 = ca * (((a0[4] + a1[4]) + (a2[4] + a3[4])) - corr) + alpha * hb1.x;
        float s5 = ca * (((a0[5] + a1[5]) + (a2[5] + a3[5])) - corr) + alpha * hb1.y;
        float s6 = ca * (((a0[6] + a1[6]) + (a2[6] + a3[6])) - corr) + alpha * hb1.z;
        float s7 = ca * (((a0[7] + a1[7]) + (a2[7] + a3[7])) - corr) + alpha * hb1.w;
        uint4 o;
        o.x = pack_bf2(s0, s1);
        o.y = pack_bf2(s2, s3);
        o.z = pack_bf2(s4, s5);
        o.w = pack_bf2(s6, s7);
        sS[g * 16 + (q ^ (g & 7))] = o;
    }
    __syncthreads();

    const int lane = t & 63;
    const int wv = t >> 6;              // wave 0..3
    const int lr = lane & 15;
    const int kg = lane >> 4;

    bf16x8 a[4];
    #pragma unroll
    for (int kb = 0; kb < 4; ++kb)
        a[kb] = ((const bf16x8*)sS)[lr * 16 + ((kb * 4 + kg) ^ (lr & 7))];

    const bf16x8* wfr = (const bf16x8*)wmt;
    #pragma unroll
    for (int j = 0; j < 2; ++j) {
        int ct = wv * 2 + j;
        f32x4 acc = (f32x4){0.f, 0.f, 0.f, 0.f};
        #pragma unroll
        for (int kb = 0; kb < 4; ++kb) {
            bf16x8 b = wfr[ct * 256 + kb * 64 + lane];
            acc = __builtin_amdgcn_mfma_f32_16x16x32_bf16(a[kb], b, acc, 0, 0, 0);
        }
        int c = ct * 16 + lr;
        #pragma unroll
        for (int reg = 0; reg < 4; ++reg) {
            int rr = base + kg * 4 + reg;
            if (rr < n) {
                size_t off = (size_t)rr * D + c;
                out[off] = acc[reg] + x[off];
            }
        }
    }
}

// ==================== TIER-2 (old CSR path) kernels ======================

__global__ __launch_bounds__(256) void k_deg(const int* __restrict__ dst,
                                             int* __restrict__ deg, int E) {
    int i = blockIdx.x * 256 + threadIdx.x;
    if (i < E) atomicAdd(&deg[dst[i]], 1);
}

__global__ __launch_bounds__(256) void k_dinv(int* dd, int n) {
    int i = blockIdx.x * 256 + threadIdx.x;
    if (i < n) {
        int d = dd[i];
        if (d < 1) d = 1;
        ((float*)dd)[i] = rsqrtf((float)d);
    }
}

__global__ __launch_bounds__(256) void k_scan1(const int* __restrict__ deg,
                                               int* __restrict__ bsum, int n) {
    __shared__ int red[256];
    int b = blockIdx.x, t = threadIdx.x;
    int base = b * 1024;
    int s = 0;
    #pragma unroll
    for (int i = 0; i < 4; ++i) {
        int idx = base + i * 256 + t;
        if (idx < n) s += deg[idx];
    }
    red[t] = s;
    __syncthreads();
    for (int k = 128; k > 0; k >>= 1) {
        if (t < k) red[t] += red[t + k];
        __syncthreads();
    }
    if (t == 0) bsum[b] = red[0];
}

__global__ void k_scan2(const int* __restrict__ bsum, int* __restrict__ boff,
                        int* __restrict__ offsets, int nb, int n) {
    if (threadIdx.x == 0) {
        int acc = 0;
        for (int i = 0; i < nb; ++i) { boff[i] = acc; acc += bsum[i]; }
        offsets[n] = acc;
    }
}

__global__ __launch_bounds__(256) void k_scan3(int* __restrict__ deg,
                                               const int* __restrict__ boff,
                                               int* __restrict__ offsets,
                                               int* __restrict__ cursor, int n) {
    __shared__ int ls[256];
    int b = blockIdx.x, t = threadIdx.x;
    int base = b * 1024 + t * 4;
    int v[4];
    #pragma unroll
    for (int i = 0; i < 4; ++i) v[i] = (base + i < n) ? deg[base + i] : 0;
    int mysum = v[0] + v[1] + v[2] + v[3];
    ls[t] = mysum;
    __syncthreads();
    for (int k = 1; k < 256; k <<= 1) {
        int add = (t >= k) ? ls[t - k] : 0;
        __syncthreads();
        ls[t] += add;
        __syncthreads();
    }
    int p = boff[b] + ls[t] - mysum;
    #pragma unroll
    for (int i = 0; i < 4; ++i) {
        if (base + i < n) {
            offsets[base + i] = p;
            cursor[base + i] = p;
            int d = v[i] < 1 ? 1 : v[i];
            ((float*)deg)[base + i] = rsqrtf((float)d);
        }
        p += v[i];
    }
}

__global__ __launch_bounds__(256) void k_csr(const int* __restrict__ src,
                                             const int* __restrict__ dst,
                                             int* __restrict__ cursor,
                                             int* __restrict__ csr_src, int E) {
    int i = blockIdx.x * 256 + threadIdx.x;
    if (i < E) {
        int pos = atomicAdd(&cursor[dst[i]], 1);
        csr_src[pos] = src[i];
    }
}

__global__ __launch_bounds__(256) void k_gather(const float4* __restrict__ x4,
                                                const int* __restrict__ csr_src,
                                                const int* __restrict__ offsets,
                                                const float* __restrict__ dinv,
                                                float4* __restrict__ hacc, int n) {
    int idx = blockIdx.x * 256 + threadIdx.x;
    int r = idx >> 5;
    if (r >= n) return;
    int q = idx & 31;
    int e0 = offsets[r], e1 = offsets[r + 1];
    float4 a0 = make_float4(0.f, 0.f, 0.f, 0.f);
    float4 a1 = make_float4(0.f, 0.f, 0.f, 0.f);
    float4 a2 = make_float4(0.f, 0.f, 0.f, 0.f);
    float4 a3 = make_float4(0.f, 0.f, 0.f, 0.f);
    int e = e0;
    for (; e + 4 <= e1; e += 4) {
        int s0 = csr_src[e + 0];
        int s1 = csr_src[e + 1];
        int s2 = csr_src[e + 2];
        int s3 = csr_src[e + 3];
        float c0 = dinv[s0], c1 = dinv[s1], c2 = dinv[s2], c3 = dinv[s3];
        float4 v0 = x4[(size_t)s0 * (D / 4) + q];
        float4 v1 = x4[(size_t)s1 * (D / 4) + q];
        float4 v2 = x4[(size_t)s2 * (D / 4) + q];
        float4 v3 = x4[(size_t)s3 * (D / 4) + q];
        a0.x += v0.x * c0; a0.y += v0.y * c0; a0.z += v0.z * c0; a0.w += v0.w * c0;
        a1.x += v1.x * c1; a1.y += v1.y * c1; a1.z += v1.z * c1; a1.w += v1.w * c1;
        a2.x += v2.x * c2; a2.y += v2.y * c2; a2.z += v2.z * c2; a2.w += v2.w * c2;
        a3.x += v3.x * c3; a3.y += v3.y * c3; a3.z += v3.z * c3; a3.w += v3.w * c3;
    }
    for (; e < e1; ++e) {
        int s = csr_src[e];
        float c = dinv[s];
        float4 v = x4[(size_t)s * (D / 4) + q];
        a0.x += v.x * c; a0.y += v.y * c; a0.z += v.z * c; a0.w += v.w * c;
    }
    float4 acc;
    acc.x = (a0.x + a1.x) + (a2.x + a3.x);
    acc.y = (a0.y + a1.y) + (a2.y + a3.y);
    acc.z = (a0.z + a1.z) + (a2.z + a3.z);
    acc.w = (a0.w + a1.w) + (a2.w + a3.w);
    hacc[(size_t)r * (D / 4) + q] = acc;
}

__global__ __launch_bounds__(256) void k_scatter(const float4* __restrict__ x4,
                                                 const int* __restrict__ src,
                                                 const int* __restrict__ dst,
                                                 const float* __restrict__ dinv,
                                                 float* hacc, int E) {
    int idx = blockIdx.x * 256 + threadIdx.x;
    int e = idx >> 5;
    if (e >= E) return;
    int q = idx & 31;
    int s = src[e];
    int t = dst[e];
    float sc = dinv[s];
    float4 v = x4[(size_t)s * (D / 4) + q];
    float* h = hacc + (size_t)t * D + q * 4;
    unsafeAtomicAdd(h + 0, v.x * sc);
    unsafeAtomicAdd(h + 1, v.y * sc);
    unsafeAtomicAdd(h + 2, v.z * sc);
    unsafeAtomicAdd(h + 3, v.w * sc);
}

// old VALU epilogue (fallback paths)
__global__ __launch_bounds__(256) void k_final(float* io,
                                               const float* __restrict__ dinv,
                                               const float* __restrict__ h0,
                                               const float* __restrict__ x,
                                               const float* __restrict__ W,
                                               const float* __restrict__ lamda_p,
                                               const float* __restrict__ alpha_p,
                                               const void* __restrict__ l_p,
                                               int n) {
    __shared__ float sW[D * D];
    __shared__ float sSup[32][D];
    const int t = threadIdx.x;

    {
        const float4* W4 = (const float4*)W;
        float4* sW4 = (float4*)sW;
        #pragma unroll
        for (int i = 0; i < (D * D / 4) / 256; ++i)
            sW4[i * 256 + t] = W4[i * 256 + t];
    }

    const float alpha = *alpha_p;
    const float lamda = *lamda_p;
    const float lf = int_or_float(l_p);
    const float theta = logf(lamda / lf + 1.0f);
    const float omt = 1.0f - theta;
    const float oma = 1.0f - alpha;

    const int base = blockIdx.x * 32;

    {
        const float4* hacc4 = (const float4*)io;
        const float4* h04 = (const float4*)h0;
        #pragma unroll
        for (int i = 0; i < 4; ++i) {
            int v = i * 256 + t;
            int tr = v >> 5;
            int q = v & 31;
            int r = base + tr;
            float4 sup = make_float4(0.f, 0.f, 0.f, 0.f);
            if (r < n) {
                float ca = oma * dinv[r];
                float4 a = hacc4[(size_t)r * (D / 4) + q];
                float4 b = h04[(size_t)r * (D / 4) + q];
                sup.x = ca * a.x + alpha * b.x;
                sup.y = ca * a.y + alpha * b.y;
                sup.z = ca * a.z + alpha * b.z;
                sup.w = ca * a.w + alpha * b.w;
            }
            *(float4*)&sSup[tr][q * 4] = sup;
        }
    }
    __syncthreads();

    const int cg = t & 31;
    const int rb = t >> 5;
    float acc[4][4] = {};
    const float4* sW4 = (const float4*)sW;
    #pragma unroll 4
    for (int k = 0; k < D; ++k) {
        float4 w = sW4[k * 32 + cg];
        #pragma unroll
        for (int j = 0; j < 4; ++j) {
            float s = sSup[rb * 4 + j][k];
            acc[j][0] += s * w.x;
            acc[j][1] += s * w.y;
            acc[j][2] += s * w.z;
            acc[j][3] += s * w.w;
        }
    }

    #pragma unroll
    for (int j = 0; j < 4; ++j) {
        int tr = rb * 4 + j;
        int r = base + tr;
        if (r < n) {
            float4 xi = ((const float4*)x)[(size_t)r * (D / 4) + cg];
            float4 sp = *(const float4*)&sSup[tr][cg * 4];
            float4 o;
            o.x = theta * acc[j][0] + omt * sp.x + xi.x;
            o.y = theta * acc[j][1] + omt * sp.y + xi.y;
            o.z = theta * acc[j][2] + omt * sp.z + xi.z;
            o.w = theta * acc[j][3] + omt * sp.w + xi.w;
            ((float4*)io)[(size_t)r * (D / 4) + cg] = o;
        }
    }
}

// ================================ host ===================================

extern "C" void kernel_launch(void* const* d_in, const int* in_sizes, int n_in,
                              void* d_out, int out_size, void* d_ws, size_t ws_size,
                              hipStream_t stream) {
    const float* x = (const float*)d_in[0];
    const int* esrc = (const int*)d_in[1];
    const int* edst = (const int*)d_in[2];
    const float* h0 = (const float*)d_in[3];
    const float* W = (const float*)d_in[4];
    const float* lamda_p = (const float*)d_in[5];
    const float* alpha_p = (const float*)d_in[6];
    const void* l_p = d_in[7];

    const int E = in_sizes[1];
    const int n = in_sizes[0] / D;

    char* w = (char*)d_ws;

    // ---- tier-1 layout ----
    size_t o_deg = 0;                                            // n ints
    size_t o_cnt = ((size_t)n * 4 + 15) & ~15ull;                // 1 int (+pad)
    size_t o_op  = o_cnt + 16;                                   // OCAP int2
    size_t o_x8g = (o_op + (size_t)OCAP * 8 + 15) & ~15ull;      // 128B guard + n*128 u8
    size_t o_sxg = (o_x8g + 128 + (size_t)n * 128 + 15) & ~15ull;// 16B guard + n floats
    size_t o_wmt = (o_sxg + 16 + (size_t)n * 4 + 15) & ~15ull;   // 32 KB
    size_t o_pl  = (o_wmt + 32768 + 15) & ~15ull;                // P_MAX*n ints
    size_t need1 = o_pl + (size_t)P_MAX * n * 4;

    if (ws_size >= need1) {
        int* deg = (int*)(w + o_deg);
        int* cnt = (int*)(w + o_cnt);
        int2* opairs = (int2*)(w + o_op);
        uint2* xs8 = (uint2*)(w + o_x8g + 128);    // row -1 = zero guard
        float* sxs = (float*)(w + o_sxg + 16);     // sxs[-1] = zero guard
        uint4* wmt = (uint4*)(w + o_wmt);
        int* planes = (int*)(w + o_pl);

        hipMemsetAsync(w, 0, o_cnt + 16, stream);   // deg + cnt

        int chunks = (E + CHUNK - 1) / CHUNK;
        k_rank<<<chunks * NSLICE, 256, 0, stream>>>(esrc, edst, deg, planes,
                                                    cnt, opairs, E, n);
        k_scale8<<<((size_t)n * 16 + 255) / 256, 256, 0, stream>>>(
            (const float4*)x, deg, xs8, sxs, planes, W, wmt, lamda_p, l_p, n);
        k_fused<<<(n + 15) / 16, 256, 0, stream>>>(
            xs8, sxs, planes, deg, cnt, opairs, h0, alpha_p, wmt,
            (float*)d_out, x, n);
        return;
    }

    // ---- tier-2: old CSR path ----
    const int nb = (n + 1023) / 1024;
    size_t t_deg = 0;
    size_t t_off = (t_deg + (size_t)n * 4 + 15) & ~15ull;
    size_t t_cur = (t_off + (size_t)(n + 1) * 4 + 15) & ~15ull;
    size_t t_bs  = (t_cur + (size_t)n * 4 + 15) & ~15ull;
    size_t t_bo  = (t_bs + (size_t)nb * 4 + 15) & ~15ull;
    size_t t_csr = (t_bo + (size_t)nb * 4 + 15) & ~15ull;
    size_t need2 = t_csr + (size_t)E * 4;

    int* deg = (int*)(w + t_deg);
    float* dinv = (float*)(w + t_deg);

    hipMemsetAsync(deg, 0, (size_t)n * sizeof(int), stream);
    k_deg<<<(E + 255) / 256, 256, 0, stream>>>(edst, deg, E);

    if (ws_size >= need2 && nb <= 1024) {
        int* offsets = (int*)(w + t_off);
        int* cursor  = (int*)(w + t_cur);
        int* bsum    = (int*)(w + t_bs);
        int* boff    = (int*)(w + t_bo);
        int* csr_src = (int*)(w + t_csr);

        k_scan1<<<nb, 256, 0, stream>>>(deg, bsum, n);
        k_scan2<<<1, 64, 0, stream>>>(bsum, boff, offsets, nb, n);
        k_scan3<<<nb, 256, 0, stream>>>(deg, boff, offsets, cursor, n);
        k_csr<<<(E + 255) / 256, 256, 0, stream>>>(esrc, edst, cursor, csr_src, E);
        k_gather<<<((size_t)n * 32 + 255) / 256, 256, 0, stream>>>(
            (const float4*)x, csr_src, offsets, dinv, (float4*)d_out, n);
    } else {
        k_dinv<<<(n + 255) / 256, 256, 0, stream>>>(deg, n);
        hipMemsetAsync(d_out, 0, (size_t)n * D * sizeof(float), stream);
        k_scatter<<<((size_t)E * 32 + 255) / 256, 256, 0, stream>>>(
            (const float4*)x, esrc, edst, dinv, (float*)d_out, E);
    }

    k_final<<<(n + 31) / 32, 256, 0, stream>>>(
        (float*)d_out, dinv, h0, x, W, lamda_p, alpha_p, l_p, n);
}